// Round 6
// baseline (240.025 us; speedup 1.0000x reference)
//
#include <hip/hip_runtime.h>

typedef _Float16 half4 __attribute__((ext_vector_type(4)));
typedef _Float16 half8 __attribute__((ext_vector_type(8)));
typedef float f32x4 __attribute__((ext_vector_type(4)));

#define NNODE 8192
#define NHID  256
#define RCAP  128
#define KCAP  64

// ================================================================ D1: init + probe + W transposes
__global__ __launch_bounds__(256) void k_fused1(
    int* deg, int* rowcnt, int* flag, const void* edges,
    const float* __restrict__ W1, _Float16* __restrict__ w1T,
    const float* __restrict__ W2, _Float16* __restrict__ w2T) {
    const int b = blockIdx.x, t = threadIdx.x;
    if (b < 32) {                       // init counters + dtype probe
        int i = b * 256 + t;
        deg[i] = 0; rowcnt[i] = 0;
        if (i == 0) {
            const long long* e = (const long long*)edges;
            int ok = 1;
            for (int k = 0; k < 64; ++k) { long long v = e[k]; if (v < 0 || v >= NNODE) ok = 0; }
            *flag = ok;
        }
    } else if (b < 32 + 512) {          // W1 [512][256] -> w1T [256][512] fp16
        int idx = (b - 32) * 256 + t;
        int k = idx >> 8, n = idx & 255;
        w1T[(size_t)n * 512 + k] = (_Float16)W1[idx];
    } else {                            // W2 [256][256] -> w2T [256][256] fp16
        int idx = (b - 544) * 256 + t;
        int k = idx >> 8, n = idx & 255;
        w2T[(size_t)n * 256 + k] = (_Float16)W2[idx];
    }
}

// ================================================================ shared GEMM body
// C[M x 256] = A[M x K] * B[K x 256]; A fp32 (split in staging) or fp16; B = BT fp16 [256][K].
#define GLS 72   // fp16 row stride: 144B = 9 quads -> conflict-free frag reads

__device__ __forceinline__ void gemm_body(
    const float* __restrict__ Af32, const _Float16* __restrict__ Ahi,
    const _Float16* __restrict__ BT, _Float16* __restrict__ Chi,
    int K, int af32, int bm, int bn) {
    __shared__ _Float16 sA[64][GLS];
    __shared__ _Float16 sB[64][GLS];
    const int t = threadIdx.x;
    const int lane = t & 63, L15 = lane & 15, q = lane >> 4;
    const int w = t >> 6, wr = w >> 1, wc = w & 1;
    f32x4 acc[2][2];
#pragma unroll
    for (int a = 0; a < 2; ++a)
#pragma unroll
        for (int b2 = 0; b2 < 2; ++b2) acc[a][b2] = (f32x4){0.f, 0.f, 0.f, 0.f};

    for (int k0 = 0; k0 < K; k0 += 64) {
        if (af32) {
#pragma unroll
            for (int i = 0; i < 4; ++i) {
                int row = i * 16 + (t >> 4), kc = (t & 15) * 4;
                float4 v = *(const float4*)(Af32 + (size_t)(bm + row) * K + k0 + kc);
                half4 h;
                h[0] = (_Float16)v.x; h[1] = (_Float16)v.y;
                h[2] = (_Float16)v.z; h[3] = (_Float16)v.w;
                *(half4*)&sA[row][kc] = h;
            }
        } else {
#pragma unroll
            for (int i = 0; i < 2; ++i) {
                int row = i * 32 + (t >> 3), ch = t & 7;
                *(half8*)&sA[row][ch * 8] =
                    *(const half8*)(Ahi + (size_t)(bm + row) * K + k0 + ch * 8);
            }
        }
#pragma unroll
        for (int i = 0; i < 2; ++i) {
            int row = i * 32 + (t >> 3), ch = t & 7;
            *(half8*)&sB[row][ch * 8] =
                *(const half8*)(BT + (size_t)(bn + row) * K + k0 + ch * 8);
        }
        __syncthreads();
#pragma unroll
        for (int ks = 0; ks < 2; ++ks) {
            const int ko = ks * 32 + q * 8;
            half8 ah[2], bh[2];
#pragma unroll
            for (int tr = 0; tr < 2; ++tr)
                ah[tr] = *(const half8*)&sA[32 * wr + 16 * tr + L15][ko];
#pragma unroll
            for (int tc = 0; tc < 2; ++tc)
                bh[tc] = *(const half8*)&sB[32 * wc + 16 * tc + L15][ko];
#pragma unroll
            for (int tr = 0; tr < 2; ++tr)
#pragma unroll
                for (int tc = 0; tc < 2; ++tc)
                    acc[tr][tc] = __builtin_amdgcn_mfma_f32_16x16x32_f16(ah[tr], bh[tc], acc[tr][tc], 0, 0, 0);
        }
        __syncthreads();
    }
#pragma unroll
    for (int tr = 0; tr < 2; ++tr)
#pragma unroll
        for (int tc = 0; tc < 2; ++tc)
#pragma unroll
            for (int r = 0; r < 4; ++r) {
                int rowg = bm + 32 * wr + 16 * tr + q * 4 + r;
                int colg = bn + 32 * wc + 16 * tc + L15;
                Chi[(size_t)rowg * NHID + colg] = (_Float16)acc[tr][tc][r];
            }
}

// ================================================================ D2: edge scatter ∥ GEMM1
__global__ __launch_bounds__(256) void k_fused2(
    const void* edges, const int* flag, int* rowcnt, int* nbr, int* deg, int E, int nbuild,
    const float* __restrict__ x, const _Float16* __restrict__ w1T, _Float16* __restrict__ X1) {
    if ((int)blockIdx.x < nbuild) {
        int i = blockIdx.x * 256 + threadIdx.x;
        int total = E + NNODE;
        if (i >= total) return;
        int r, c;
        if (i < E) {
            if (*flag) {
                const long long* e = (const long long*)edges;
                r = (int)e[i]; c = (int)e[E + i];
            } else {
                const int* e = (const int*)edges;
                r = e[i]; c = e[E + i];
            }
        } else { r = i - E; c = r; }
        int pos = atomicAdd(&rowcnt[r], 1);
        if (pos < RCAP) nbr[r * RCAP + pos] = c;
        atomicAdd(&deg[c], 1);
    } else {
        int g = blockIdx.x - nbuild;          // 0..511 -> 128x4 tile grid
        gemm_body(x, nullptr, w1T, X1, 512, 1, (g >> 2) * 64, (g & 3) * 64);
    }
}

// ================================================================ D5: standalone GEMM (layer 2)
__global__ __launch_bounds__(256) void k_gemm(
    const _Float16* __restrict__ Ahi, const _Float16* __restrict__ BT,
    _Float16* __restrict__ Chi, int K) {
    gemm_body(nullptr, Ahi, BT, Chi, K, 0, blockIdx.x * 64, blockIdx.y * 64);
}

// ================================================================ D3: dedup + weights + top-64 (2 rows/block)
__global__ __launch_bounds__(256) void k_dedup(const int* __restrict__ nbr,
                                               const int* __restrict__ rowcnt,
                                               const int* __restrict__ deg,
                                               int* __restrict__ cols,
                                               float* __restrict__ wout,
                                               float* __restrict__ rsum) {
    __shared__ int lc[2][RCAP];
    __shared__ float lw[2][RCAP];
    __shared__ unsigned char kp[2][RCAP];
    __shared__ int s_cw[2][2];
    __shared__ float s_rw[2][2];
    const int t = threadIdx.x;
    const int half = t >> 7, st = t & 127;
    const int wid = st >> 6, lane = t & 63;
    const int r = blockIdx.x * 2 + half;
    int n = rowcnt[r]; if (n > RCAP) n = RCAP;
    if (st < n) lc[half][st] = nbr[r * RCAP + st];
    __syncthreads();
    float dr = 1.f / sqrtf((float)deg[r]);
    bool keep = false; float wv = 0.f;
    if (st < n) {
        int c = lc[half][st];
        int mult = 0; bool first = true;
        for (int i = 0; i < n; ++i) {
            int ci = lc[half][i];
            if (ci == c) { mult++; if (i < st) first = false; }
        }
        keep = first;
        if (first) wv = (float)mult * dr * (1.f / sqrtf((float)deg[c]));
    }
    kp[half][st] = keep ? 1 : 0; lw[half][st] = wv;
    float rv = wv;
#pragma unroll
    for (int d = 1; d < 64; d <<= 1) rv += __shfl_xor(rv, d, 64);
    unsigned long long b = __ballot(keep);
    int pre = __popcll(b & ((1ull << lane) - 1ull));
    int cw = __popcll(b);
    if (lane == 0) { s_cw[half][wid] = cw; s_rw[half][wid] = rv; }
    __syncthreads();
    int total = s_cw[half][0] + s_cw[half][1];
    if (st == 0) rsum[r] = s_rw[half][0] + s_rw[half][1];
    const int base = r * KCAP;
    if (total <= KCAP) {
        int off = (wid ? s_cw[half][0] : 0) + pre;
        if (keep) { cols[base + off] = lc[half][st]; wout[base + off] = wv; }
        for (int m = total + st; m < KCAP; m += 128) { cols[base + m] = r; wout[base + m] = 0.f; }
    } else if (st == 0) {
        for (int s = 0; s < KCAP; ++s) {
            int best = -1;
            for (int i = 0; i < n; ++i) {
                if (!kp[half][i]) continue;
                if (best < 0 || lw[half][i] > lw[half][best] ||
                    (lw[half][i] == lw[half][best] && lc[half][i] < lc[half][best])) best = i;
            }
            cols[base + s] = lc[half][best]; wout[base + s] = lw[half][best]; kp[half][best] = 0;
        }
    }
}

// ================================================================ fused soft-k-medoid + bias + relu
#define MS 264   // fp16 row stride: 528B = 33 quads -> conflict-free frag reads

__global__ __launch_bounds__(256, 4) void k_medoid(
    const _Float16* __restrict__ Xhi,
    const float* __restrict__ bias,
    float* __restrict__ OutF, _Float16* __restrict__ OutHi,
    const int* __restrict__ cols, const float* __restrict__ wts,
    const float* __restrict__ rsum, int writeH) {
    __shared__ _Float16 sh[64][MS];
    __shared__ float s_a[64];
    __shared__ float s_sq[64];
    __shared__ float s_cpart[2][64];
    __shared__ float s_u[64];
    __shared__ int   s_cols[64];
    __shared__ float s_red[4][288];   // [wave][9*oct+e] padded stride

    const int node = blockIdx.x;
    const int t = threadIdx.x;
    const int w = t >> 6, lane = t & 63;
    const int L15 = lane & 15, q = lane >> 4;
    const int wr = w >> 1, wc = w & 1;

    if (t < 64) { s_cols[t] = cols[node * KCAP + t]; s_a[t] = wts[node * KCAP + t]; }
    __syncthreads();

    // gather 64 rows x 256 dims fp16 + fused sq computation (== MFMA diagonal numerics:
    // fp32 accumulation of squares of the same fp16 values)
    {
        const int ch = t & 31, rr = t >> 5;
        float ps[8];
#pragma unroll
        for (int i = 0; i < 8; ++i) {
            int l = i * 8 + rr;
            half8 v = *(const half8*)(Xhi + ((size_t)s_cols[l] << 8) + ch * 8);
            *(half8*)&sh[l][ch * 8] = v;
            float s = 0.f;
#pragma unroll
            for (int e = 0; e < 8; ++e) { float f = (float)v[e]; s = fmaf(f, f, s); }
            ps[i] = s;
        }
#pragma unroll
        for (int d = 1; d < 32; d <<= 1)
#pragma unroll
            for (int i = 0; i < 8; ++i) ps[i] += __shfl_xor(ps[i], d, 64);
        if (ch == 0) {
#pragma unroll
            for (int i = 0; i < 8; ++i) s_sq[i * 8 + rr] = ps[i];
        }
    }
    __syncthreads();

    // Gram: wave = one 32x32 quadrant (2x2 of 16x16), single fp16 product, K=256
    f32x4 acc[2][2];
#pragma unroll
    for (int a = 0; a < 2; ++a)
#pragma unroll
        for (int b = 0; b < 2; ++b) acc[a][b] = (f32x4){0.f, 0.f, 0.f, 0.f};
#pragma unroll
    for (int ks = 0; ks < 8; ++ks) {
        const int ko = ks * 32 + q * 8;
        half8 ah[2], bh[2];
#pragma unroll
        for (int tr = 0; tr < 2; ++tr) ah[tr] = *(const half8*)&sh[32 * wr + 16 * tr + L15][ko];
#pragma unroll
        for (int tc = 0; tc < 2; ++tc) bh[tc] = *(const half8*)&sh[32 * wc + 16 * tc + L15][ko];
#pragma unroll
        for (int tr = 0; tr < 2; ++tr)
#pragma unroll
            for (int tc = 0; tc < 2; ++tc)
                acc[tr][tc] = __builtin_amdgcn_mfma_f32_16x16x32_f16(ah[tr], bh[tc], acc[tr][tc], 0, 0, 0);
    }

    // dist + weighted column sums — no barrier needed: uses own-wave acc + prebuilt s_sq/s_a
#pragma unroll
    for (int tc = 0; tc < 2; ++tc) {
        const int colg = 32 * wc + 16 * tc + L15;
        const float sqc = s_sq[colg];
        float pj = 0.f;
#pragma unroll
        for (int tr = 0; tr < 2; ++tr)
#pragma unroll
            for (int r = 0; r < 4; ++r) {
                int rowg = 32 * wr + 16 * tr + q * 4 + r;
                float d2 = s_sq[rowg] + sqc - 2.f * acc[tr][tc][r];
                float dist = d2 > 0.f ? __builtin_amdgcn_sqrtf(d2) : 0.f;
                pj = fmaf(s_a[rowg], dist, pj);
            }
        pj += __shfl_xor(pj, 16, 64);
        pj += __shfl_xor(pj, 32, 64);
        if (q == 0) s_cpart[wr][colg] = pj;
    }
    __syncthreads();

    // softmax(-c) * a, renormalized (softmax denom cancels), * row_sum
    if (w == 0) {
        int j = lane;
        float c = s_cpart[0][j] + s_cpart[1][j];
        float aj = s_a[j];
        bool valid = aj > 0.f;
        float cv = valid ? c : 3.4e38f;
        float mn = cv;
#pragma unroll
        for (int d = 1; d < 64; d <<= 1) mn = fminf(mn, __shfl_xor(mn, d, 64));
        float e = valid ? __expf(mn - c) * aj : 0.f;
        float s = e;
#pragma unroll
        for (int d = 1; d < 64; d <<= 1) s += __shfl_xor(s, d, 64);
        s_u[j] = e * (rsum[node] / s);
    }
    __syncthreads();

    // epilogue: out[d] = sum_j u[j]*x_j[d]; thread = (8-dim octet) x (8-j block)
    const int oct = t & 31, jb = t >> 5;
    float accd[8] = {0.f, 0.f, 0.f, 0.f, 0.f, 0.f, 0.f, 0.f};
#pragma unroll
    for (int jj = 0; jj < 8; ++jj) {
        int j = jb * 8 + jj;
        float u = s_u[j];
        half8 xv = *(const half8*)&sh[j][8 * oct];
#pragma unroll
        for (int e = 0; e < 8; ++e) accd[e] = fmaf(u, (float)xv[e], accd[e]);
    }
#pragma unroll
    for (int e = 0; e < 8; ++e) accd[e] += __shfl_xor(accd[e], 32, 64);
    if (lane < 32) {
#pragma unroll
        for (int e = 0; e < 8; ++e) s_red[w][9 * oct + e] = accd[e];
    }
    __syncthreads();
    const int idx = 9 * (t >> 3) + (t & 7);
    float o = s_red[0][idx] + s_red[1][idx] + s_red[2][idx] + s_red[3][idx];
    float res = fmaxf(o + bias[t], 0.f);
    size_t oi = (size_t)node * NHID + t;
    if (writeH) OutHi[oi] = (_Float16)res;
    else        OutF[oi] = res;
}

// ================================================================ launch
extern "C" void kernel_launch(void* const* d_in, const int* in_sizes, int n_in,
                              void* d_out, int out_size, void* d_ws, size_t ws_size,
                              hipStream_t stream) {
    const float* x  = (const float*)d_in[0];
    const void*  ei = d_in[1];
    const float* W1 = (const float*)d_in[2];
    const float* b1 = (const float*)d_in[3];
    const float* W2 = (const float*)d_in[4];
    const float* b2 = (const float*)d_in[5];
    float* out = (float*)d_out;
    const int E = in_sizes[1] / 2;

    char* p = (char*)d_ws;
    auto alloc = [&](size_t bytes) { char* q = p; p += (bytes + 255) & ~(size_t)255; return q; };
    int*      deg    = (int*)alloc((size_t)NNODE * 4);
    int*      rowcnt = (int*)alloc((size_t)NNODE * 4);
    int*      flag   = (int*)alloc(256);
    int*      colsA  = (int*)alloc((size_t)NNODE * KCAP * 4);
    float*    wA     = (float*)alloc((size_t)NNODE * KCAP * 4);
    float*    rsum   = (float*)alloc((size_t)NNODE * 4);
    _Float16* w1T    = (_Float16*)alloc((size_t)512 * NHID * 2);
    _Float16* w2T    = (_Float16*)alloc((size_t)NHID * NHID * 2);
    _Float16* X1hi   = (_Float16*)alloc((size_t)NNODE * NHID * 2);   // also X2
    _Float16* Hhi    = (_Float16*)alloc((size_t)NNODE * NHID * 2);
    int*      nbr    = (int*)alloc((size_t)NNODE * RCAP * 4);

    const int nbuild = (E + NNODE + 255) / 256;

    // D1: init ∥ W1 transpose ∥ W2 transpose
    k_fused1<<<32 + 512 + 256, 256, 0, stream>>>(deg, rowcnt, flag, ei, W1, w1T, W2, w2T);
    // D2: edge scatter ∥ GEMM1
    k_fused2<<<nbuild + 512, 256, 0, stream>>>(ei, flag, rowcnt, nbr, deg, E, nbuild, x, w1T, X1hi);
    // D3: dedup (2 rows/block)
    k_dedup<<<NNODE / 2, 256, 0, stream>>>(nbr, rowcnt, deg, colsA, wA, rsum);
    // D4-D6
    k_medoid<<<NNODE, 256, 0, stream>>>(X1hi, b1, nullptr, Hhi, colsA, wA, rsum, 1);
    k_gemm<<<dim3(NNODE / 64, NHID / 64), 256, 0, stream>>>(Hhi, w2T, X1hi, 256);
    k_medoid<<<NNODE, 256, 0, stream>>>(X1hi, b2, out, nullptr, colsA, wA, rsum, 0);
}

// Round 7
// 218.392 us; speedup vs baseline: 1.0991x; 1.0991x over previous
//
#include <hip/hip_runtime.h>

typedef _Float16 half4 __attribute__((ext_vector_type(4)));
typedef _Float16 half8 __attribute__((ext_vector_type(8)));
typedef float f32x4 __attribute__((ext_vector_type(4)));

#define NNODE 8192
#define NHID  256
#define RCAP  128
#define KCAP  64

// ================================================================ D1: init + probe + W transposes
__global__ __launch_bounds__(256) void k_fused1(
    int* deg, int* rowcnt, int* flag, const void* edges,
    const float* __restrict__ W1, _Float16* __restrict__ w1T,
    const float* __restrict__ W2, _Float16* __restrict__ w2T) {
    const int b = blockIdx.x, t = threadIdx.x;
    if (b < 32) {
        int i = b * 256 + t;
        deg[i] = 0; rowcnt[i] = 0;
        if (i == 0) {
            const long long* e = (const long long*)edges;
            int ok = 1;
            for (int k = 0; k < 64; ++k) { long long v = e[k]; if (v < 0 || v >= NNODE) ok = 0; }
            *flag = ok;
        }
    } else if (b < 32 + 512) {          // W1 [512][256] -> w1T [256][512]
        int idx = (b - 32) * 256 + t;
        int k = idx >> 8, n = idx & 255;
        w1T[(size_t)n * 512 + k] = (_Float16)W1[idx];
    } else {                            // W2 [256][256] -> w2T [256][256]
        int idx = (b - 544) * 256 + t;
        int k = idx >> 8, n = idx & 255;
        w2T[(size_t)n * 256 + k] = (_Float16)W2[idx];
    }
}

// ================================================================ shared GEMM body
#define GLS 72   // fp16 row stride: 144B = 9 quads -> conflict-free frag reads

__device__ __forceinline__ void gemm_body(
    const float* __restrict__ Af32, const _Float16* __restrict__ Ahi,
    const _Float16* __restrict__ BT, _Float16* __restrict__ Chi,
    int K, int af32, int bm, int bn) {
    __shared__ _Float16 sA[64][GLS];
    __shared__ _Float16 sB[64][GLS];
    const int t = threadIdx.x;
    const int lane = t & 63, L15 = lane & 15, q = lane >> 4;
    const int w = t >> 6, wr = w >> 1, wc = w & 1;
    f32x4 acc[2][2];
#pragma unroll
    for (int a = 0; a < 2; ++a)
#pragma unroll
        for (int b2 = 0; b2 < 2; ++b2) acc[a][b2] = (f32x4){0.f, 0.f, 0.f, 0.f};

    for (int k0 = 0; k0 < K; k0 += 64) {
        if (af32) {
#pragma unroll
            for (int i = 0; i < 4; ++i) {
                int row = i * 16 + (t >> 4), kc = (t & 15) * 4;
                float4 v = *(const float4*)(Af32 + (size_t)(bm + row) * K + k0 + kc);
                half4 h;
                h[0] = (_Float16)v.x; h[1] = (_Float16)v.y;
                h[2] = (_Float16)v.z; h[3] = (_Float16)v.w;
                *(half4*)&sA[row][kc] = h;
            }
        } else {
#pragma unroll
            for (int i = 0; i < 2; ++i) {
                int row = i * 32 + (t >> 3), ch = t & 7;
                *(half8*)&sA[row][ch * 8] =
                    *(const half8*)(Ahi + (size_t)(bm + row) * K + k0 + ch * 8);
            }
        }
#pragma unroll
        for (int i = 0; i < 2; ++i) {
            int row = i * 32 + (t >> 3), ch = t & 7;
            *(half8*)&sB[row][ch * 8] =
                *(const half8*)(BT + (size_t)(bn + row) * K + k0 + ch * 8);
        }
        __syncthreads();
#pragma unroll
        for (int ks = 0; ks < 2; ++ks) {
            const int ko = ks * 32 + q * 8;
            half8 ah[2], bh[2];
#pragma unroll
            for (int tr = 0; tr < 2; ++tr)
                ah[tr] = *(const half8*)&sA[32 * wr + 16 * tr + L15][ko];
#pragma unroll
            for (int tc = 0; tc < 2; ++tc)
                bh[tc] = *(const half8*)&sB[32 * wc + 16 * tc + L15][ko];
#pragma unroll
            for (int tr = 0; tr < 2; ++tr)
#pragma unroll
                for (int tc = 0; tc < 2; ++tc)
                    acc[tr][tc] = __builtin_amdgcn_mfma_f32_16x16x32_f16(ah[tr], bh[tc], acc[tr][tc], 0, 0, 0);
        }
        __syncthreads();
    }
#pragma unroll
    for (int tr = 0; tr < 2; ++tr)
#pragma unroll
        for (int tc = 0; tc < 2; ++tc)
#pragma unroll
            for (int r = 0; r < 4; ++r) {
                int rowg = bm + 32 * wr + 16 * tr + q * 4 + r;
                int colg = bn + 32 * wc + 16 * tc + L15;
                Chi[(size_t)rowg * NHID + colg] = (_Float16)acc[tr][tc][r];
            }
}

// ================================================================ D2: edge scatter ∥ GEMM1
__global__ __launch_bounds__(256) void k_fused2(
    const void* edges, const int* flag, int* rowcnt, int* nbr, int* deg, int E, int nbuild,
    const float* __restrict__ x, const _Float16* __restrict__ w1T, _Float16* __restrict__ X1) {
    if ((int)blockIdx.x < nbuild) {
        int i = blockIdx.x * 256 + threadIdx.x;
        int total = E + NNODE;
        if (i >= total) return;
        int r, c;
        if (i < E) {
            if (*flag) {
                const long long* e = (const long long*)edges;
                r = (int)e[i]; c = (int)e[E + i];
            } else {
                const int* e = (const int*)edges;
                r = e[i]; c = e[E + i];
            }
        } else { r = i - E; c = r; }
        int pos = atomicAdd(&rowcnt[r], 1);
        if (pos < RCAP) nbr[r * RCAP + pos] = c;
        atomicAdd(&deg[c], 1);
    } else {
        int g = blockIdx.x - nbuild;
        gemm_body(x, nullptr, w1T, X1, 512, 1, (g >> 2) * 64, (g & 3) * 64);
    }
}

// ================================================================ D5: standalone GEMM (layer 2)
__global__ __launch_bounds__(256) void k_gemm(
    const _Float16* __restrict__ Ahi, const _Float16* __restrict__ BT,
    _Float16* __restrict__ Chi, int K) {
    gemm_body(nullptr, Ahi, BT, Chi, K, 0, blockIdx.x * 64, blockIdx.y * 64);
}

// ================================================================ D3: dedup + weights + top-64 (2 rows/block)
__global__ __launch_bounds__(256) void k_dedup(const int* __restrict__ nbr,
                                               const int* __restrict__ rowcnt,
                                               const int* __restrict__ deg,
                                               int* __restrict__ cols,
                                               float* __restrict__ wout,
                                               float* __restrict__ rsum,
                                               int* __restrict__ ncnt) {
    __shared__ int lc[2][RCAP];
    __shared__ float lw[2][RCAP];
    __shared__ unsigned char kp[2][RCAP];
    __shared__ int s_cw[2][2];
    __shared__ float s_rw[2][2];
    const int t = threadIdx.x;
    const int half = t >> 7, st = t & 127;
    const int wid = st >> 6, lane = t & 63;
    const int r = blockIdx.x * 2 + half;
    int n = rowcnt[r]; if (n > RCAP) n = RCAP;
    if (st < n) lc[half][st] = nbr[r * RCAP + st];
    __syncthreads();
    float dr = 1.f / sqrtf((float)deg[r]);
    bool keep = false; float wv = 0.f;
    if (st < n) {
        int c = lc[half][st];
        int mult = 0; bool first = true;
        for (int i = 0; i < n; ++i) {
            int ci = lc[half][i];
            if (ci == c) { mult++; if (i < st) first = false; }
        }
        keep = first;
        if (first) wv = (float)mult * dr * (1.f / sqrtf((float)deg[c]));
    }
    kp[half][st] = keep ? 1 : 0; lw[half][st] = wv;
    float rv = wv;
#pragma unroll
    for (int d = 1; d < 64; d <<= 1) rv += __shfl_xor(rv, d, 64);
    unsigned long long b = __ballot(keep);
    int pre = __popcll(b & ((1ull << lane) - 1ull));
    int cw = __popcll(b);
    if (lane == 0) { s_cw[half][wid] = cw; s_rw[half][wid] = rv; }
    __syncthreads();
    int total = s_cw[half][0] + s_cw[half][1];
    if (st == 0) { rsum[r] = s_rw[half][0] + s_rw[half][1]; ncnt[r] = total; }
    const int base = r * KCAP;
    if (total <= KCAP) {
        int off = (wid ? s_cw[half][0] : 0) + pre;
        if (keep) { cols[base + off] = lc[half][st]; wout[base + off] = wv; }
        for (int m = total + st; m < KCAP; m += 128) { cols[base + m] = r; wout[base + m] = 0.f; }
    } else if (st == 0) {
        for (int s = 0; s < KCAP; ++s) {
            int best = -1;
            for (int i = 0; i < n; ++i) {
                if (!kp[half][i]) continue;
                if (best < 0 || lw[half][i] > lw[half][best] ||
                    (lw[half][i] == lw[half][best] && lc[half][i] < lc[half][best])) best = i;
            }
            cols[base + s] = lc[half][best]; wout[base + s] = lw[half][best]; kp[half][best] = 0;
        }
    }
}

// ================================================================ fused soft-k-medoid + bias + relu
// Dual path: n<=32 nodes (≈47%, Poisson deg) use a 32-row Gram — exact, since
// padding cols have a=0 and contribute nothing downstream.
#define MS 264   // fp16 row stride: 528B = 33 quads -> conflict-free frag reads

__global__ __launch_bounds__(256, 4) void k_medoid(
    const _Float16* __restrict__ Xhi,
    const float* __restrict__ bias,
    float* __restrict__ OutF, _Float16* __restrict__ OutHi,
    const int* __restrict__ cols, const float* __restrict__ wts,
    const float* __restrict__ rsum, const int* __restrict__ ncnt, int writeH) {
    __shared__ _Float16 sh[64][MS];
    __shared__ float s_a[64];
    __shared__ float s_sq[64];
    __shared__ float s_cpart[2][64];
    __shared__ float s_u[64];
    __shared__ int   s_cols[64];
    __shared__ float s_red[4][288];

    const int node = blockIdx.x;
    const int t = threadIdx.x;
    const int w = t >> 6, lane = t & 63;
    const int L15 = lane & 15, q = lane >> 4;
    const int wr = w >> 1, wc = w & 1;
    const bool small = (ncnt[node] <= 32);   // block-uniform

    if (t < 64) { s_cols[t] = cols[node * KCAP + t]; s_a[t] = wts[node * KCAP + t]; }
    __syncthreads();

    // gather (rows 0..31 only on fast path)
    {
        const int ch = t & 31, rr = t >> 5;
        if (small) {
#pragma unroll
            for (int i = 0; i < 4; ++i) {
                int l = i * 8 + rr;
                *(half8*)&sh[l][ch * 8] = *(const half8*)(Xhi + ((size_t)s_cols[l] << 8) + ch * 8);
            }
        } else {
#pragma unroll
            for (int i = 0; i < 8; ++i) {
                int l = i * 8 + rr;
                *(half8*)&sh[l][ch * 8] = *(const half8*)(Xhi + ((size_t)s_cols[l] << 8) + ch * 8);
            }
        }
    }
    __syncthreads();

    if (small) {
        // ---- 32x32 Gram: wave = one 16x16 tile, K=256
        f32x4 acc = (f32x4){0.f, 0.f, 0.f, 0.f};
#pragma unroll
        for (int ks = 0; ks < 8; ++ks) {
            const int ko = ks * 32 + q * 8;
            half8 ah = *(const half8*)&sh[16 * wr + L15][ko];
            half8 bh = *(const half8*)&sh[16 * wc + L15][ko];
            acc = __builtin_amdgcn_mfma_f32_16x16x32_f16(ah, bh, acc, 0, 0, 0);
        }
        if (wr == wc) {
#pragma unroll
            for (int r = 0; r < 4; ++r)
                if (L15 == q * 4 + r) s_sq[16 * wr + L15] = acc[r];
        }
        __syncthreads();
        f32x4 sq4 = *(const f32x4*)&s_sq[16 * wr + 4 * q];
        f32x4 a4  = *(const f32x4*)&s_a [16 * wr + 4 * q];
        const float sqc = s_sq[16 * wc + L15];
        float pj = 0.f;
#pragma unroll
        for (int r = 0; r < 4; ++r) {
            float d2 = sq4[r] + sqc - 2.f * acc[r];
            float dist = d2 > 0.f ? __builtin_amdgcn_sqrtf(d2) : 0.f;
            pj = fmaf(a4[r], dist, pj);
        }
        pj += __shfl_xor(pj, 16, 64);
        pj += __shfl_xor(pj, 32, 64);
        if (q == 0) s_cpart[wr][16 * wc + L15] = pj;
        // cols 32..63 of s_cpart stay stale; softmax masks them via a=0
    } else {
        // ---- 64x64 Gram: wave = one 32x32 quadrant (2x2 of 16x16), K=256
        f32x4 acc[2][2];
#pragma unroll
        for (int a = 0; a < 2; ++a)
#pragma unroll
            for (int b = 0; b < 2; ++b) acc[a][b] = (f32x4){0.f, 0.f, 0.f, 0.f};
#pragma unroll
        for (int ks = 0; ks < 8; ++ks) {
            const int ko = ks * 32 + q * 8;
            half8 ah[2], bh[2];
#pragma unroll
            for (int tr = 0; tr < 2; ++tr) ah[tr] = *(const half8*)&sh[32 * wr + 16 * tr + L15][ko];
#pragma unroll
            for (int tc = 0; tc < 2; ++tc) bh[tc] = *(const half8*)&sh[32 * wc + 16 * tc + L15][ko];
#pragma unroll
            for (int tr = 0; tr < 2; ++tr)
#pragma unroll
                for (int tc = 0; tc < 2; ++tc)
                    acc[tr][tc] = __builtin_amdgcn_mfma_f32_16x16x32_f16(ah[tr], bh[tc], acc[tr][tc], 0, 0, 0);
        }
#pragma unroll
        for (int tr = 0; tr < 2; ++tr)
#pragma unroll
            for (int tc = 0; tc < 2; ++tc)
                if (32 * wr + 16 * tr == 32 * wc + 16 * tc) {
#pragma unroll
                    for (int r = 0; r < 4; ++r)
                        if (L15 == q * 4 + r) s_sq[32 * wr + 16 * tr + L15] = acc[tr][tc][r];
                }
        __syncthreads();
        f32x4 sq4[2], a4[2];
#pragma unroll
        for (int tr = 0; tr < 2; ++tr) {
            sq4[tr] = *(const f32x4*)&s_sq[32 * wr + 16 * tr + 4 * q];
            a4[tr]  = *(const f32x4*)&s_a [32 * wr + 16 * tr + 4 * q];
        }
#pragma unroll
        for (int tc = 0; tc < 2; ++tc) {
            const int colg = 32 * wc + 16 * tc + L15;
            const float sqc = s_sq[colg];
            float pj = 0.f;
#pragma unroll
            for (int tr = 0; tr < 2; ++tr)
#pragma unroll
                for (int r = 0; r < 4; ++r) {
                    float d2 = sq4[tr][r] + sqc - 2.f * acc[tr][tc][r];
                    float dist = d2 > 0.f ? __builtin_amdgcn_sqrtf(d2) : 0.f;
                    pj = fmaf(a4[tr][r], dist, pj);
                }
            pj += __shfl_xor(pj, 16, 64);
            pj += __shfl_xor(pj, 32, 64);
            if (q == 0) s_cpart[wr][colg] = pj;
        }
    }
    __syncthreads();

    // softmax(-c) * a, renormalized (softmax denom cancels), * row_sum
    if (w == 0) {
        int j = lane;
        float c = s_cpart[0][j] + s_cpart[1][j];
        float aj = s_a[j];
        bool valid = aj > 0.f;
        float cv = valid ? c : 3.4e38f;
        float mn = cv;
#pragma unroll
        for (int d = 1; d < 64; d <<= 1) mn = fminf(mn, __shfl_xor(mn, d, 64));
        float e = valid ? __expf(mn - c) * aj : 0.f;
        float s = e;
#pragma unroll
        for (int d = 1; d < 64; d <<= 1) s += __shfl_xor(s, d, 64);
        s_u[j] = e * (rsum[node] / s);
    }
    __syncthreads();

    // epilogue: out[d] = sum_j u[j]*x_j[d]; thread = (8-dim octet) x (8-j block)
    const int oct = t & 31, jb = t >> 5;
    float accd[8] = {0.f, 0.f, 0.f, 0.f, 0.f, 0.f, 0.f, 0.f};
    if (!small || jb < 4) {
#pragma unroll
        for (int jj = 0; jj < 8; ++jj) {
            int j = jb * 8 + jj;
            float u = s_u[j];
            half8 xv = *(const half8*)&sh[j][8 * oct];
#pragma unroll
            for (int e = 0; e < 8; ++e) accd[e] = fmaf(u, (float)xv[e], accd[e]);
        }
    }
#pragma unroll
    for (int e = 0; e < 8; ++e) accd[e] += __shfl_xor(accd[e], 32, 64);
    if (lane < 32) {
#pragma unroll
        for (int e = 0; e < 8; ++e) s_red[w][9 * oct + e] = accd[e];
    }
    __syncthreads();
    const int idx = 9 * (t >> 3) + (t & 7);
    float o = s_red[0][idx] + s_red[1][idx] + s_red[2][idx] + s_red[3][idx];
    float res = fmaxf(o + bias[t], 0.f);
    size_t oi = (size_t)node * NHID + t;
    if (writeH) OutHi[oi] = (_Float16)res;
    else        OutF[oi] = res;
}

// ================================================================ launch
extern "C" void kernel_launch(void* const* d_in, const int* in_sizes, int n_in,
                              void* d_out, int out_size, void* d_ws, size_t ws_size,
                              hipStream_t stream) {
    const float* x  = (const float*)d_in[0];
    const void*  ei = d_in[1];
    const float* W1 = (const float*)d_in[2];
    const float* b1 = (const float*)d_in[3];
    const float* W2 = (const float*)d_in[4];
    const float* b2 = (const float*)d_in[5];
    float* out = (float*)d_out;
    const int E = in_sizes[1] / 2;

    char* p = (char*)d_ws;
    auto alloc = [&](size_t bytes) { char* q = p; p += (bytes + 255) & ~(size_t)255; return q; };
    int*      deg    = (int*)alloc((size_t)NNODE * 4);
    int*      rowcnt = (int*)alloc((size_t)NNODE * 4);
    int*      flag   = (int*)alloc(256);
    int*      colsA  = (int*)alloc((size_t)NNODE * KCAP * 4);
    float*    wA     = (float*)alloc((size_t)NNODE * KCAP * 4);
    float*    rsum   = (float*)alloc((size_t)NNODE * 4);
    int*      ncnt   = (int*)alloc((size_t)NNODE * 4);
    _Float16* w1T    = (_Float16*)alloc((size_t)512 * NHID * 2);
    _Float16* w2T    = (_Float16*)alloc((size_t)NHID * NHID * 2);
    _Float16* X1hi   = (_Float16*)alloc((size_t)NNODE * NHID * 2);   // also X2
    _Float16* Hhi    = (_Float16*)alloc((size_t)NNODE * NHID * 2);
    int*      nbr    = (int*)alloc((size_t)NNODE * RCAP * 4);

    const int nbuild = (E + NNODE + 255) / 256;

    k_fused1<<<32 + 512 + 256, 256, 0, stream>>>(deg, rowcnt, flag, ei, W1, w1T, W2, w2T);
    k_fused2<<<nbuild + 512, 256, 0, stream>>>(ei, flag, rowcnt, nbr, deg, E, nbuild, x, w1T, X1hi);
    k_dedup<<<NNODE / 2, 256, 0, stream>>>(nbr, rowcnt, deg, colsA, wA, rsum, ncnt);
    k_medoid<<<NNODE, 256, 0, stream>>>(X1hi, b1, nullptr, Hhi, colsA, wA, rsum, ncnt, 1);
    k_gemm<<<dim3(NNODE / 64, NHID / 64), 256, 0, stream>>>(Hhi, w2T, X1hi, 256);
    k_medoid<<<NNODE, 256, 0, stream>>>(X1hi, b2, out, nullptr, colsA, wA, rsum, ncnt, 0);
}

// Round 8
// 214.565 us; speedup vs baseline: 1.1187x; 1.0178x over previous
//
#include <hip/hip_runtime.h>

typedef _Float16 half4 __attribute__((ext_vector_type(4)));
typedef _Float16 half8 __attribute__((ext_vector_type(8)));
typedef float f32x4 __attribute__((ext_vector_type(4)));

#define NNODE 8192
#define NHID  256
#define RCAP  128
#define KCAP  64

// ================================================================ D1: init + probe + W transposes + x->fp16
__global__ __launch_bounds__(256) void k_fused1(
    int* deg, int* rowcnt, int* flag, const void* edges,
    const float* __restrict__ W1, _Float16* __restrict__ w1T,
    const float* __restrict__ W2, _Float16* __restrict__ w2T,
    const float* __restrict__ x, _Float16* __restrict__ xh) {
    const int b = blockIdx.x, t = threadIdx.x;
    if (b < 32) {
        int i = b * 256 + t;
        deg[i] = 0; rowcnt[i] = 0;
        if (i == 0) {
            const long long* e = (const long long*)edges;
            int ok = 1;
            for (int k = 0; k < 64; ++k) { long long v = e[k]; if (v < 0 || v >= NNODE) ok = 0; }
            *flag = ok;
        }
    } else if (b < 32 + 4096) {         // x [8192][512] fp32 -> fp16
        int i = (b - 32) * 256 + t;     // float4 index
        float4 v = ((const float4*)x)[i];
        half4 h;
        h[0] = (_Float16)v.x; h[1] = (_Float16)v.y;
        h[2] = (_Float16)v.z; h[3] = (_Float16)v.w;
        *(half4*)&xh[4 * (size_t)i] = h;
    } else if (b < 32 + 4096 + 512) {   // W1 [512][256] -> w1T [256][512]
        int idx = (b - 4128) * 256 + t;
        int k = idx >> 8, n = idx & 255;
        w1T[(size_t)n * 512 + k] = (_Float16)W1[idx];
    } else {                            // W2 [256][256] -> w2T [256][256]
        int idx = (b - 4640) * 256 + t;
        int k = idx >> 8, n = idx & 255;
        w2T[(size_t)n * 256 + k] = (_Float16)W2[idx];
    }
}

// ================================================================ shared GEMM body (fp16 A, fp16 BT)
#define GLS 72   // fp16 row stride: 144B = 9 quads -> conflict-free frag reads

__device__ __forceinline__ void gemm_body(
    const _Float16* __restrict__ Ahi, const _Float16* __restrict__ BT,
    _Float16* __restrict__ Chi, int K, int bm, int bn) {
    __shared__ _Float16 sA[64][GLS];
    __shared__ _Float16 sB[64][GLS];
    const int t = threadIdx.x;
    const int lane = t & 63, L15 = lane & 15, q = lane >> 4;
    const int w = t >> 6, wr = w >> 1, wc = w & 1;
    f32x4 acc[2][2];
#pragma unroll
    for (int a = 0; a < 2; ++a)
#pragma unroll
        for (int b2 = 0; b2 < 2; ++b2) acc[a][b2] = (f32x4){0.f, 0.f, 0.f, 0.f};

    for (int k0 = 0; k0 < K; k0 += 64) {
#pragma unroll
        for (int i = 0; i < 2; ++i) {
            int row = i * 32 + (t >> 3), ch = t & 7;
            *(half8*)&sA[row][ch * 8] =
                *(const half8*)(Ahi + (size_t)(bm + row) * K + k0 + ch * 8);
            *(half8*)&sB[row][ch * 8] =
                *(const half8*)(BT + (size_t)(bn + row) * K + k0 + ch * 8);
        }
        __syncthreads();
#pragma unroll
        for (int ks = 0; ks < 2; ++ks) {
            const int ko = ks * 32 + q * 8;
            half8 ah[2], bh[2];
#pragma unroll
            for (int tr = 0; tr < 2; ++tr)
                ah[tr] = *(const half8*)&sA[32 * wr + 16 * tr + L15][ko];
#pragma unroll
            for (int tc = 0; tc < 2; ++tc)
                bh[tc] = *(const half8*)&sB[32 * wc + 16 * tc + L15][ko];
#pragma unroll
            for (int tr = 0; tr < 2; ++tr)
#pragma unroll
                for (int tc = 0; tc < 2; ++tc)
                    acc[tr][tc] = __builtin_amdgcn_mfma_f32_16x16x32_f16(ah[tr], bh[tc], acc[tr][tc], 0, 0, 0);
        }
        __syncthreads();
    }
#pragma unroll
    for (int tr = 0; tr < 2; ++tr)
#pragma unroll
        for (int tc = 0; tc < 2; ++tc)
#pragma unroll
            for (int r = 0; r < 4; ++r) {
                int rowg = bm + 32 * wr + 16 * tr + q * 4 + r;
                int colg = bn + 32 * wc + 16 * tc + L15;
                Chi[(size_t)rowg * NHID + colg] = (_Float16)acc[tr][tc][r];
            }
}

// ================================================================ D2: edge scatter ∥ GEMM1
__global__ __launch_bounds__(256) void k_fused2(
    const void* edges, const int* flag, int* rowcnt, int* nbr, int* deg, int E, int nbuild,
    const _Float16* __restrict__ xh, const _Float16* __restrict__ w1T, _Float16* __restrict__ X1) {
    if ((int)blockIdx.x < nbuild) {
        int i = blockIdx.x * 256 + threadIdx.x;
        int total = E + NNODE;
        if (i >= total) return;
        int r, c;
        if (i < E) {
            if (*flag) {
                const long long* e = (const long long*)edges;
                r = (int)e[i]; c = (int)e[E + i];
            } else {
                const int* e = (const int*)edges;
                r = e[i]; c = e[E + i];
            }
        } else { r = i - E; c = r; }
        int pos = atomicAdd(&rowcnt[r], 1);
        if (pos < RCAP) nbr[r * RCAP + pos] = c;
        atomicAdd(&deg[c], 1);
    } else {
        int g = blockIdx.x - nbuild;
        gemm_body(xh, w1T, X1, 512, (g >> 2) * 64, (g & 3) * 64);
    }
}

// ================================================================ D5: standalone GEMM (layer 2)
__global__ __launch_bounds__(256) void k_gemm(
    const _Float16* __restrict__ Ahi, const _Float16* __restrict__ BT,
    _Float16* __restrict__ Chi, int K) {
    gemm_body(Ahi, BT, Chi, K, blockIdx.x * 64, blockIdx.y * 64);
}

// ================================================================ D3: dedup + weights + top-64 (2 rows/block)
__global__ __launch_bounds__(256) void k_dedup(const int* __restrict__ nbr,
                                               const int* __restrict__ rowcnt,
                                               const int* __restrict__ deg,
                                               int* __restrict__ cols,
                                               float* __restrict__ wout,
                                               float* __restrict__ rsum) {
    __shared__ int lc[2][RCAP];
    __shared__ float lw[2][RCAP];
    __shared__ unsigned char kp[2][RCAP];
    __shared__ int s_cw[2][2];
    __shared__ float s_rw[2][2];
    const int t = threadIdx.x;
    const int half = t >> 7, st = t & 127;
    const int wid = st >> 6, lane = t & 63;
    const int r = blockIdx.x * 2 + half;
    int n = rowcnt[r]; if (n > RCAP) n = RCAP;
    if (st < n) lc[half][st] = nbr[r * RCAP + st];
    __syncthreads();
    float dr = 1.f / sqrtf((float)deg[r]);
    bool keep = false; float wv = 0.f;
    if (st < n) {
        int c = lc[half][st];
        int mult = 0; bool first = true;
        for (int i = 0; i < n; ++i) {
            int ci = lc[half][i];
            if (ci == c) { mult++; if (i < st) first = false; }
        }
        keep = first;
        if (first) wv = (float)mult * dr * (1.f / sqrtf((float)deg[c]));
    }
    kp[half][st] = keep ? 1 : 0; lw[half][st] = wv;
    float rv = wv;
#pragma unroll
    for (int d = 1; d < 64; d <<= 1) rv += __shfl_xor(rv, d, 64);
    unsigned long long b = __ballot(keep);
    int pre = __popcll(b & ((1ull << lane) - 1ull));
    int cw = __popcll(b);
    if (lane == 0) { s_cw[half][wid] = cw; s_rw[half][wid] = rv; }
    __syncthreads();
    int total = s_cw[half][0] + s_cw[half][1];
    if (st == 0) rsum[r] = s_rw[half][0] + s_rw[half][1];
    const int base = r * KCAP;
    if (total <= KCAP) {
        int off = (wid ? s_cw[half][0] : 0) + pre;
        if (keep) { cols[base + off] = lc[half][st]; wout[base + off] = wv; }
        for (int m = total + st; m < KCAP; m += 128) { cols[base + m] = r; wout[base + m] = 0.f; }
    } else if (st == 0) {
        for (int s = 0; s < KCAP; ++s) {
            int best = -1;
            for (int i = 0; i < n; ++i) {
                if (!kp[half][i]) continue;
                if (best < 0 || lw[half][i] > lw[half][best] ||
                    (lw[half][i] == lw[half][best] && lc[half][i] < lc[half][best])) best = i;
            }
            cols[base + s] = lc[half][best]; wout[base + s] = lw[half][best]; kp[half][best] = 0;
        }
    }
}

// ================================================================ fused soft-k-medoid + bias + relu
// Half-K LDS tile (two gather+Gram phases, acc carried): ~23.5 KB -> 6 blocks/CU.
// Epilogue: dims 128-255 from resident LDS (phase 1), dims 0-127 re-read from global (L2-hot).
#define SK 136   // fp16 row stride: 272B = 17 quads -> consecutive rows cycle bank-quads

__global__ __launch_bounds__(256, 6) void k_medoid(
    const _Float16* __restrict__ Xhi,
    const float* __restrict__ bias,
    float* __restrict__ OutF, _Float16* __restrict__ OutHi,
    const int* __restrict__ cols, const float* __restrict__ wts,
    const float* __restrict__ rsum, int writeH) {
    __shared__ _Float16 sh[64][SK];
    __shared__ float s_a[64];
    __shared__ float s_sq[64];
    __shared__ float s_cpart[2][64];
    __shared__ float s_u[64];
    __shared__ int   s_cols[64];
    __shared__ float s_red[4][288];

    const int node = blockIdx.x;
    const int t = threadIdx.x;
    const int w = t >> 6, lane = t & 63;
    const int L15 = lane & 15, q = lane >> 4;
    const int wr = w >> 1, wc = w & 1;

    if (t < 64) { s_cols[t] = cols[node * KCAP + t]; s_a[t] = wts[node * KCAP + t]; }
    __syncthreads();

    f32x4 acc[2][2];
#pragma unroll
    for (int a = 0; a < 2; ++a)
#pragma unroll
        for (int b = 0; b < 2; ++b) acc[a][b] = (f32x4){0.f, 0.f, 0.f, 0.f};

    const int ch = t & 15, rr = t >> 4;
    for (int phase = 0; phase < 2; ++phase) {
        // gather 64 rows x 128 dims fp16
#pragma unroll
        for (int i = 0; i < 4; ++i) {
            int l = i * 16 + rr;
            *(half8*)&sh[l][ch * 8] =
                *(const half8*)(Xhi + ((size_t)s_cols[l] << 8) + phase * 128 + ch * 8);
        }
        __syncthreads();
        // Gram quadrant per wave, acc carried across phases
#pragma unroll
        for (int ks = 0; ks < 4; ++ks) {
            const int ko = ks * 32 + q * 8;
            half8 ah[2], bh[2];
#pragma unroll
            for (int tr = 0; tr < 2; ++tr) ah[tr] = *(const half8*)&sh[32 * wr + 16 * tr + L15][ko];
#pragma unroll
            for (int tc = 0; tc < 2; ++tc) bh[tc] = *(const half8*)&sh[32 * wc + 16 * tc + L15][ko];
#pragma unroll
            for (int tr = 0; tr < 2; ++tr)
#pragma unroll
                for (int tc = 0; tc < 2; ++tc)
                    acc[tr][tc] = __builtin_amdgcn_mfma_f32_16x16x32_f16(ah[tr], bh[tc], acc[tr][tc], 0, 0, 0);
        }
        if (phase == 0) __syncthreads();   // protect sh before phase-1 gather overwrites
    }
    // sh now holds dims 128..255 — reused by the epilogue.

    // diagonal -> s_sq
#pragma unroll
    for (int tr = 0; tr < 2; ++tr)
#pragma unroll
        for (int tc = 0; tc < 2; ++tc)
            if (32 * wr + 16 * tr == 32 * wc + 16 * tc) {
#pragma unroll
                for (int r = 0; r < 4; ++r)
                    if (L15 == q * 4 + r) s_sq[32 * wr + 16 * tr + L15] = acc[tr][tc][r];
            }
    __syncthreads();

    // dist + weighted column sums
    f32x4 sq4[2], a4[2];
#pragma unroll
    for (int tr = 0; tr < 2; ++tr) {
        sq4[tr] = *(const f32x4*)&s_sq[32 * wr + 16 * tr + 4 * q];
        a4[tr]  = *(const f32x4*)&s_a [32 * wr + 16 * tr + 4 * q];
    }
#pragma unroll
    for (int tc = 0; tc < 2; ++tc) {
        const int colg = 32 * wc + 16 * tc + L15;
        const float sqc = s_sq[colg];
        float pj = 0.f;
#pragma unroll
        for (int tr = 0; tr < 2; ++tr)
#pragma unroll
            for (int r = 0; r < 4; ++r) {
                float d2 = sq4[tr][r] + sqc - 2.f * acc[tr][tc][r];
                float dist = d2 > 0.f ? __builtin_amdgcn_sqrtf(d2) : 0.f;
                pj = fmaf(a4[tr][r], dist, pj);
            }
        pj += __shfl_xor(pj, 16, 64);
        pj += __shfl_xor(pj, 32, 64);
        if (q == 0) s_cpart[wr][colg] = pj;
    }
    __syncthreads();

    // softmax(-c) * a, renormalized (softmax denom cancels), * row_sum
    if (w == 0) {
        int j = lane;
        float c = s_cpart[0][j] + s_cpart[1][j];
        float aj = s_a[j];
        bool valid = aj > 0.f;
        float cv = valid ? c : 3.4e38f;
        float mn = cv;
#pragma unroll
        for (int d = 1; d < 64; d <<= 1) mn = fminf(mn, __shfl_xor(mn, d, 64));
        float e = valid ? __expf(mn - c) * aj : 0.f;
        float s = e;
#pragma unroll
        for (int d = 1; d < 64; d <<= 1) s += __shfl_xor(s, d, 64);
        s_u[j] = e * (rsum[node] / s);
    }
    __syncthreads();

    // epilogue: out[d] = sum_j u[j]*x_j[d]; thread = (8-dim octet) x (8-j block)
    // oct 0..15 -> dims 0..127 from global; oct 16..31 -> dims 128..255 from LDS
    const int oct = t & 31, jb = t >> 5;
    float accd[8] = {0.f, 0.f, 0.f, 0.f, 0.f, 0.f, 0.f, 0.f};
#pragma unroll
    for (int jj = 0; jj < 8; ++jj) {
        int j = jb * 8 + jj;
        float u = s_u[j];
        half8 xv;
        if (oct < 16) xv = *(const half8*)(Xhi + ((size_t)s_cols[j] << 8) + oct * 8);
        else          xv = *(const half8*)&sh[j][(oct - 16) * 8];
#pragma unroll
        for (int e = 0; e < 8; ++e) accd[e] = fmaf(u, (float)xv[e], accd[e]);
    }
#pragma unroll
    for (int e = 0; e < 8; ++e) accd[e] += __shfl_xor(accd[e], 32, 64);
    if (lane < 32) {
#pragma unroll
        for (int e = 0; e < 8; ++e) s_red[w][9 * oct + e] = accd[e];
    }
    __syncthreads();
    const int idx = 9 * (t >> 3) + (t & 7);
    float o = s_red[0][idx] + s_red[1][idx] + s_red[2][idx] + s_red[3][idx];
    float res = fmaxf(o + bias[t], 0.f);
    size_t oi = (size_t)node * NHID + t;
    if (writeH) OutHi[oi] = (_Float16)res;
    else        OutF[oi] = res;
}

// ================================================================ launch
extern "C" void kernel_launch(void* const* d_in, const int* in_sizes, int n_in,
                              void* d_out, int out_size, void* d_ws, size_t ws_size,
                              hipStream_t stream) {
    const float* x  = (const float*)d_in[0];
    const void*  ei = d_in[1];
    const float* W1 = (const float*)d_in[2];
    const float* b1 = (const float*)d_in[3];
    const float* W2 = (const float*)d_in[4];
    const float* b2 = (const float*)d_in[5];
    float* out = (float*)d_out;
    const int E = in_sizes[1] / 2;

    char* p = (char*)d_ws;
    auto alloc = [&](size_t bytes) { char* q = p; p += (bytes + 255) & ~(size_t)255; return q; };
    int*      deg    = (int*)alloc((size_t)NNODE * 4);
    int*      rowcnt = (int*)alloc((size_t)NNODE * 4);
    int*      flag   = (int*)alloc(256);
    int*      colsA  = (int*)alloc((size_t)NNODE * KCAP * 4);
    float*    wA     = (float*)alloc((size_t)NNODE * KCAP * 4);
    float*    rsum   = (float*)alloc((size_t)NNODE * 4);
    _Float16* xh     = (_Float16*)alloc((size_t)NNODE * 512 * 2);
    _Float16* w1T    = (_Float16*)alloc((size_t)512 * NHID * 2);
    _Float16* w2T    = (_Float16*)alloc((size_t)NHID * NHID * 2);
    _Float16* X1hi   = (_Float16*)alloc((size_t)NNODE * NHID * 2);   // also X2
    _Float16* Hhi    = (_Float16*)alloc((size_t)NNODE * NHID * 2);
    int*      nbr    = (int*)alloc((size_t)NNODE * RCAP * 4);

    const int nbuild = (E + NNODE + 255) / 256;

    k_fused1<<<32 + 4096 + 512 + 256, 256, 0, stream>>>(deg, rowcnt, flag, ei, W1, w1T, W2, w2T, x, xh);
    k_fused2<<<nbuild + 512, 256, 0, stream>>>(ei, flag, rowcnt, nbr, deg, E, nbuild, xh, w1T, X1hi);
    k_dedup<<<NNODE / 2, 256, 0, stream>>>(nbr, rowcnt, deg, colsA, wA, rsum);
    k_medoid<<<NNODE, 256, 0, stream>>>(X1hi, b1, nullptr, Hhi, colsA, wA, rsum, 1);
    k_gemm<<<dim3(NNODE / 64, NHID / 64), 256, 0, stream>>>(Hhi, w2T, X1hi, 256);
    k_medoid<<<NNODE, 256, 0, stream>>>(X1hi, b2, out, nullptr, colsA, wA, rsum, 0);
}